// Round 2
// baseline (2344.994 us; speedup 1.0000x reference)
//
#include <hip/hip_runtime.h>
#include <cstdint>

#define UNITS 128
#define GATES 512            // 4*UNITS
#define IN_DIM 128
#define BATCH 64
#define SEQ 2048
#define ROWS (BATCH * SEQ)   // 131072

typedef _Float16 f16;
typedef _Float16 f16x2 __attribute__((ext_vector_type(2)));
typedef _Float16 f16x8 __attribute__((ext_vector_type(8)));
typedef float    f32x4 __attribute__((ext_vector_type(4)));

static __device__ __forceinline__ float sigmoid_f(float x) {
    float e = __builtin_amdgcn_exp2f(-1.44269504f * x);
    return __builtin_amdgcn_rcpf(1.0f + e);
}
static __device__ __forceinline__ float tanh_f(float x) {
    float e = __builtin_amdgcn_exp2f(2.8853900817779268f * x);
    return 1.0f - 2.0f * __builtin_amdgcn_rcpf(1.0f + e);
}

// Workgroup barrier that orders LDS only: skips __syncthreads()'s
// s_waitcnt vmcnt(0), so xp prefetch and out[] stores stay in flight.
static __device__ __forceinline__ void lds_barrier() {
    __asm__ volatile("s_waitcnt lgkmcnt(0)\n\ts_barrier" ::: "memory");
}

// ---------------------------------------------------------------------------
// Kernel 1: WxT[n][k] = (f16)W[k][n] for k<128 ; WhT[n][k-128] for k>=128.
// Coalesced f32 read, scattered f16 transpose writes (one-time, tiny).
// ---------------------------------------------------------------------------
__global__ void wt_kernel(const float* __restrict__ W,
                          f16* __restrict__ WxT,
                          f16* __restrict__ WhT) {
    int idx = blockIdx.x * 256 + threadIdx.x;     // 0 .. 131071 over W (256x512)
    int k = idx >> 9, n = idx & 511;
    f16 v = (f16)W[idx];
    if (k < IN_DIM) WxT[n * IN_DIM + k] = v;
    else            WhT[n * IN_DIM + (k - IN_DIM)] = v;
}

// ---------------------------------------------------------------------------
// xp fragment-layout address: value (row=b*SEQ+t, col) lands exactly where
// the scan's consuming lane reads it with 2 coalesced dwordx4 per step.
//   scan block sb = b>>4, sample-in-block sm = b&15 -> C-frag row q*4+r
//   lane_t = (sm>>2)*16 + (col&15), elem = (col>>7)*4 + (sm&3)
// addr16 = (((sb*SEQ + t)*8 + wave)*64 + lane_t)*16 + elem
// ---------------------------------------------------------------------------
static __device__ __forceinline__ size_t xp_frag_addr(int row, int col) {
    int b  = row >> 11;          // SEQ = 2048
    int t  = row & 2047;
    int sb = b >> 4;
    int sm = b & 15;
    int g  = col >> 7;
    int w  = (col >> 4) & 7;
    int m16c = col & 15;
    int lane_t = ((sm >> 2) << 4) + m16c;
    int r_t    = sm & 3;
    return ((((size_t)sb * SEQ + t) * 8 + w) * 64 + lane_t) * 16 + g * 4 + r_t;
}

// ---------------------------------------------------------------------------
// Kernel 2: xp = data @ Wx + b, f16 out in FRAGMENT layout (see above).
// Compute identical to the verified version; only the store addressing
// changed (was scattered 2B stores before, still scattered 2B stores).
// ---------------------------------------------------------------------------
__global__ __launch_bounds__(256) void xp_gemm(
        const float* __restrict__ A,      // data f32, ROWS x 128
        const f16*  __restrict__ WxT,     // 512 x 128 f16
        const float* __restrict__ bias,   // 512 f32
        f16* __restrict__ xp) {
    const int wave = threadIdx.x >> 6;
    const int lane = threadIdx.x & 63;
    const int m16  = lane & 15;
    const int q    = lane >> 4;
    const int rowBase = blockIdx.x * 128 + wave * 32;

    f16x8 a[2][4];
    #pragma unroll
    for (int mc = 0; mc < 2; ++mc)
        #pragma unroll
        for (int ks = 0; ks < 4; ++ks) {
            const float* p = A + (size_t)(rowBase + mc * 16 + m16) * IN_DIM
                               + ks * 32 + q * 8;
            float4 lo = *(const float4*)p;
            float4 hi = *(const float4*)(p + 4);
            f16x8 v;
            v[0] = (f16)lo.x; v[1] = (f16)lo.y; v[2] = (f16)lo.z; v[3] = (f16)lo.w;
            v[4] = (f16)hi.x; v[5] = (f16)hi.y; v[6] = (f16)hi.z; v[7] = (f16)hi.w;
            a[mc][ks] = v;
        }

    for (int nt = 0; nt < 32; ++nt) {
        f16x8 bfr[4];
        #pragma unroll
        for (int ks = 0; ks < 4; ++ks)
            bfr[ks] = *(const f16x8*)(WxT + (nt * 16 + m16) * IN_DIM + ks * 32 + q * 8);
        f32x4 acc0 = {0.f, 0.f, 0.f, 0.f}, acc1 = {0.f, 0.f, 0.f, 0.f};
        #pragma unroll
        for (int ks = 0; ks < 4; ++ks) {
            acc0 = __builtin_amdgcn_mfma_f32_16x16x32_f16(a[0][ks], bfr[ks], acc0, 0, 0, 0);
            acc1 = __builtin_amdgcn_mfma_f32_16x16x32_f16(a[1][ks], bfr[ks], acc1, 0, 0, 0);
        }
        const int col = nt * 16 + m16;
        float bv = bias[col];
        #pragma unroll
        for (int r = 0; r < 4; ++r) {
            int row0 = rowBase + q * 4 + r;
            xp[xp_frag_addr(row0,      col)] = (f16)(acc0[r] + bv);
            xp[xp_frag_addr(row0 + 16, col)] = (f16)(acc1[r] + bv);
        }
    }
}

// ---------------------------------------------------------------------------
// Kernel 3 (NEW): MFMA batched scan. 4 blocks x 16 samples, 8 waves (512 thr).
//
// Round-2 theory: per-SIMD issue is invariant to wave count with 1 sample/
// block — the fix is batching. Per step: z[16x512] = h[16x128] @ Wh + xp,
// as 16 mfma_f32_16x16x32_f16 per wave (4 gate N-tiles x 4 K-steps),
// mirroring xp_gemm's verified fragment layout exactly.
//   wave w owns cells w*16..w*16+15, tiles g=0..3 = gates i,f,o,g
//   lane (q,m16): C rows q*4+r = samples, col = cell w*16+m16
//   -> all 4 gates of each (sample,cell) pair are IN-REGISTER: no shuffles.
// h double-buffered in LDS, XOR-swizzled (chunk ^= row&7): a linear
// [16][128] f16 tile read as A-frags is a 16-way bank conflict; swizzle
// makes reads ~2-way (free) on both read and write sides.
// xp pre-swizzled to fragment order by xp_gemm: 2 coalesced dwordx4 per
// lane per step, prefetch distance 2 (HBM ~900cy ~ 2 steps).
// Nonlinearities: 8 trans/pair (shared rcp for sig(i)*tanh(g) and
// sig(o)*tanh(c)); tanh args clamped +-16 so exp2 can't reach inf (the
// (e-1)*rcp(...inf) = inf*0 = NaN hazard); sigmoid args need no clamp
// (inf propagates to a clean 0 contribution through rcp).
// ---------------------------------------------------------------------------
__global__ __launch_bounds__(512, 2) void lstm_scan_mfma(
        const f16* __restrict__ WhT,      // 512 x 128 f16  (Wh transposed)
        const f16* __restrict__ xpf,      // fragment-layout xp (f16)
        float* __restrict__ out) {        // ROWS x 128 f32
    __shared__ __align__(16) f16 hbuf[2][16 * UNITS];   // 8 KiB, swizzled

    const int tid  = threadIdx.x;
    const int sb   = blockIdx.x;          // 0..3 : samples sb*16..sb*16+15
    const int w    = tid >> 6;
    const int lane = tid & 63;
    const int q    = lane >> 4;
    const int m16  = lane & 15;
    const int cell = w * 16 + m16;        // [0,128)
    const int cc_chunk = cell >> 3;       // logical chunk of the cell
    const int cc_in    = cell & 7;

    // B-frags: Wh columns for 4 gate tiles x 4 K-steps -> 64 VGPRs.
    f16x8 bfr[4][4];
    #pragma unroll
    for (int g = 0; g < 4; ++g)
        #pragma unroll
        for (int ks = 0; ks < 4; ++ks)
            bfr[g][ks] = *(const f16x8*)(WhT
                + (size_t)(g * 128 + cell) * IN_DIM + ks * 32 + q * 8);

    float c[4] = {1.f, 1.f, 1.f, 1.f};    // reference: c0 = ones

    // h0 = zeros (swizzle irrelevant for zeros)
    #pragma unroll
    for (int i = 0; i < 4; ++i) hbuf[0][tid * 4 + i] = (f16)0.f;

    // per-lane xp base; step stride = 8 waves * 64 lanes * 16 elems = 8192 f16
    const f16* xb = xpf + ((size_t)sb * SEQ * 8 + w) * 1024 + (size_t)lane * 16;
    f16x8 xA0 = *(const f16x8*)(xb);
    f16x8 xA1 = *(const f16x8*)(xb + 8);
    f16x8 xB0 = *(const f16x8*)(xb + 8192);
    f16x8 xB1 = *(const f16x8*)(xb + 8192 + 8);

    __syncthreads();

    const float L2E = 1.44269504f;

    for (int t = 0; t < SEQ; ++t) {
        const int cur = t & 1, nxt = cur ^ 1;

        // prefetch xp(t+2), clamped (no OOB)
        size_t t2 = (size_t)((t + 2 < SEQ) ? (t + 2) : (SEQ - 1));
        f16x8 xC0 = *(const f16x8*)(xb + t2 * 8192);
        f16x8 xC1 = *(const f16x8*)(xb + t2 * 8192 + 8);

        // A-frags: row = m16, k = ks*32 + q*8 .. +8  (swizzled chunk)
        f16x8 afr[4];
        #pragma unroll
        for (int ks = 0; ks < 4; ++ks)
            afr[ks] = *(const f16x8*)(&hbuf[cur]
                [m16 * UNITS + (((ks * 4 + q) ^ (m16 & 7)) << 3)]);

        f32x4 acc[4] = {{0.f,0.f,0.f,0.f},{0.f,0.f,0.f,0.f},
                        {0.f,0.f,0.f,0.f},{0.f,0.f,0.f,0.f}};
        #pragma unroll
        for (int ks = 0; ks < 4; ++ks) {
            acc[0] = __builtin_amdgcn_mfma_f32_16x16x32_f16(afr[ks], bfr[0][ks], acc[0], 0, 0, 0);
            acc[1] = __builtin_amdgcn_mfma_f32_16x16x32_f16(afr[ks], bfr[1][ks], acc[1], 0, 0, 0);
            acc[2] = __builtin_amdgcn_mfma_f32_16x16x32_f16(afr[ks], bfr[2][ks], acc[2], 0, 0, 0);
            acc[3] = __builtin_amdgcn_mfma_f32_16x16x32_f16(afr[ks], bfr[3][ks], acc[3], 0, 0, 0);
        }

        // epilogue: 4 (sample,cell) pairs per lane, all gates in-register
        #pragma unroll
        for (int r = 0; r < 4; ++r) {
            float zi = acc[0][r] + (float)xA0[r];
            float zf = acc[1][r] + (float)xA0[4 + r];
            float zo = acc[2][r] + (float)xA1[r];
            float zg = acc[3][r] + (float)xA1[4 + r];

            float ei = __builtin_amdgcn_exp2f(-L2E * zi);
            float ef = __builtin_amdgcn_exp2f(-L2E * zf);
            float eo = __builtin_amdgcn_exp2f(-L2E * zo);
            float zgc = fminf(fmaxf(zg, -16.f), 16.f);
            float eg = __builtin_amdgcn_exp2f(2.f * L2E * zgc);

            float rf  = __builtin_amdgcn_rcpf(1.f + ef);
            float rig = __builtin_amdgcn_rcpf((1.f + ei) * (1.f + eg));
            float cn  = c[r] * rf + (eg - 1.f) * rig;   // sig(f)*c + sig(i)*tanh(g)
            c[r] = cn;

            float ccl = fminf(fmaxf(cn, -16.f), 16.f);
            float ec  = __builtin_amdgcn_exp2f(2.f * L2E * ccl);
            float h   = (ec - 1.f)
                      * __builtin_amdgcn_rcpf((1.f + eo) * (1.f + ec)); // sig(o)*tanh(c)

            const int row = q * 4 + r;                  // sample-in-block
            hbuf[nxt][row * UNITS + ((cc_chunk ^ (row & 7)) << 3) + cc_in] = (f16)h;
            out[((size_t)(sb * 16 + row) * SEQ + t) * UNITS + cell] = h;
        }

        xA0 = xB0; xA1 = xB1;
        xB0 = xC0; xB1 = xC1;
        lds_barrier();   // LDS-only ordering: xp prefetch + out stores stay in flight
    }
}

// ---------------------------------------------------------------------------
// Fallback (workspace too small): fused 4-wave scan, Wx register-resident.
// Unchanged from the verified earlier version.
// ---------------------------------------------------------------------------
__global__ __launch_bounds__(256, 1) void lstm_scan_fused(
        const float* __restrict__ W,      // 256 x 512 f32
        const float* __restrict__ bias,   // 512 f32
        const float* __restrict__ data,   // ROWS x 128 f32
        float* __restrict__ out) {        // ROWS x 128 f32
    __shared__ __align__(16) f16 h_lds[2][UNITS];
    __shared__ __align__(16) f16 x_lds[2][UNITS];

    const int tid  = threadIdx.x;
    const int b    = blockIdx.x;
    const int wave = tid >> 6;
    const int lane = tid & 63;
    const int half = lane >> 5;
    const int cell = wave * 32 + (lane & 31);
    const int c0   = cell + half * 256;
    const int c1   = c0 + 128;

    f16x2 wh0[64], wh1[64];
    #pragma unroll
    for (int k = 0; k < 64; ++k) {
        wh0[k] = f16x2{(f16)W[(size_t)(IN_DIM + 2 * k) * GATES + c0],
                       (f16)W[(size_t)(IN_DIM + 2 * k + 1) * GATES + c0]};
        wh1[k] = f16x2{(f16)W[(size_t)(IN_DIM + 2 * k) * GATES + c1],
                       (f16)W[(size_t)(IN_DIM + 2 * k + 1) * GATES + c1]};
    }
    f16x2 wxa[64], wxb[64];
    #pragma unroll
    for (int k = 0; k < 64; ++k) {
        wxa[k] = f16x2{(f16)W[(size_t)(2 * k) * GATES + c0],
                       (f16)W[(size_t)(2 * k + 1) * GATES + c0]};
        wxb[k] = f16x2{(f16)W[(size_t)(2 * k) * GATES + c1],
                       (f16)W[(size_t)(2 * k + 1) * GATES + c1]};
    }
    float bb0 = bias[c0];
    float bb1 = bias[c1];

    float c = 1.0f;
    if (tid < UNITS) h_lds[0][tid] = (f16)0.f;
    if (tid < UNITS)
        x_lds[0][tid] = (f16)data[(size_t)b * SEQ * IN_DIM + tid];
    __syncthreads();

    for (int t = 0; t < SEQ; ++t) {
        const int cur = t & 1, nxt = cur ^ 1;
        float a00 = bb0, a01 = 0.f, a10 = bb1, a11 = 0.f;

        {
            const uint4* xsrc = (const uint4*)(&x_lds[cur][0]);
            uint4 xb[16];
            #pragma unroll
            for (int i = 0; i < 16; ++i) xb[i] = xsrc[i];
            #pragma unroll
            for (int i = 0; i < 16; ++i) {
                f16x2 p0 = __builtin_bit_cast(f16x2, xb[i].x);
                f16x2 p1 = __builtin_bit_cast(f16x2, xb[i].y);
                f16x2 p2 = __builtin_bit_cast(f16x2, xb[i].z);
                f16x2 p3 = __builtin_bit_cast(f16x2, xb[i].w);
                const int k = 4 * i;
                if (i < 8) {
                    a00 = __builtin_amdgcn_fdot2(p0, wxa[k],     a00, false);
                    a10 = __builtin_amdgcn_fdot2(p0, wxb[k],     a10, false);
                    a00 = __builtin_amdgcn_fdot2(p1, wxa[k + 1], a00, false);
                    a10 = __builtin_amdgcn_fdot2(p1, wxb[k + 1], a10, false);
                    a00 = __builtin_amdgcn_fdot2(p2, wxa[k + 2], a00, false);
                    a10 = __builtin_amdgcn_fdot2(p2, wxb[k + 2], a10, false);
                    a00 = __builtin_amdgcn_fdot2(p3, wxa[k + 3], a00, false);
                    a10 = __builtin_amdgcn_fdot2(p3, wxb[k + 3], a10, false);
                } else {
                    a01 = __builtin_amdgcn_fdot2(p0, wxa[k],     a01, false);
                    a11 = __builtin_amdgcn_fdot2(p0, wxb[k],     a11, false);
                    a01 = __builtin_amdgcn_fdot2(p1, wxa[k + 1], a01, false);
                    a11 = __builtin_amdgcn_fdot2(p1, wxb[k + 1], a11, false);
                    a01 = __builtin_amdgcn_fdot2(p2, wxa[k + 2], a01, false);
                    a11 = __builtin_amdgcn_fdot2(p2, wxb[k + 2], a11, false);
                    a01 = __builtin_amdgcn_fdot2(p3, wxa[k + 3], a01, false);
                    a11 = __builtin_amdgcn_fdot2(p3, wxb[k + 3], a11, false);
                }
            }
        }
        {
            const uint4* hsrc = (const uint4*)(&h_lds[cur][0]);
            uint4 hb[16];
            #pragma unroll
            for (int i = 0; i < 16; ++i) hb[i] = hsrc[i];
            #pragma unroll
            for (int i = 0; i < 16; ++i) {
                f16x2 p0 = __builtin_bit_cast(f16x2, hb[i].x);
                f16x2 p1 = __builtin_bit_cast(f16x2, hb[i].y);
                f16x2 p2 = __builtin_bit_cast(f16x2, hb[i].z);
                f16x2 p3 = __builtin_bit_cast(f16x2, hb[i].w);
                const int k = 4 * i;
                if (i < 8) {
                    a00 = __builtin_amdgcn_fdot2(p0, wh0[k],     a00, false);
                    a10 = __builtin_amdgcn_fdot2(p0, wh1[k],     a10, false);
                    a00 = __builtin_amdgcn_fdot2(p1, wh0[k + 1], a00, false);
                    a10 = __builtin_amdgcn_fdot2(p1, wh1[k + 1], a10, false);
                    a00 = __builtin_amdgcn_fdot2(p2, wh0[k + 2], a00, false);
                    a10 = __builtin_amdgcn_fdot2(p2, wh1[k + 2], a10, false);
                    a00 = __builtin_amdgcn_fdot2(p3, wh0[k + 3], a00, false);
                    a10 = __builtin_amdgcn_fdot2(p3, wh1[k + 3], a10, false);
                } else {
                    a01 = __builtin_amdgcn_fdot2(p0, wh0[k],     a01, false);
                    a11 = __builtin_amdgcn_fdot2(p0, wh1[k],     a11, false);
                    a01 = __builtin_amdgcn_fdot2(p1, wh0[k + 1], a01, false);
                    a11 = __builtin_amdgcn_fdot2(p1, wh1[k + 1], a11, false);
                    a01 = __builtin_amdgcn_fdot2(p2, wh0[k + 2], a01, false);
                    a11 = __builtin_amdgcn_fdot2(p2, wh1[k + 2], a11, false);
                    a01 = __builtin_amdgcn_fdot2(p3, wh0[k + 3], a01, false);
                    a11 = __builtin_amdgcn_fdot2(p3, wh1[k + 3], a11, false);
                }
            }
        }
        float z0 = a00 + a01, z1 = a10 + a11;

        float s0 = sigmoid_f(z0);
        float s1 = (half == 0) ? sigmoid_f(z1) : tanh_f(z1);
        float p0 = __shfl_xor(s0, 32, 64);
        float p1 = __shfl_xor(s1, 32, 64);

        if (half == 0) {
            c = s1 * c + s0 * p1;
            float h = p0 * tanh_f(c);
            h_lds[nxt][cell] = (f16)h;
            out[((size_t)b * SEQ + t) * UNITS + cell] = h;
        }
        if (tid < UNITS) {
            int t1 = (t + 1 < SEQ) ? (t + 1) : t;
            x_lds[nxt][tid] = (f16)data[(size_t)b * SEQ * IN_DIM
                                        + (size_t)t1 * IN_DIM + tid];
        }
        lds_barrier();
    }
}

// ---------------------------------------------------------------------------
extern "C" void kernel_launch(void* const* d_in, const int* in_sizes, int n_in,
                              void* d_out, int out_size, void* d_ws, size_t ws_size,
                              hipStream_t stream) {
    const float* data = (const float*)d_in[0];   // f32 (64,2048,128)
    const float* W    = (const float*)d_in[1];   // f32 (256,512)
    const float* bias = (const float*)d_in[2];   // f32 (512,)
    float* out = (float*)d_out;                  // f32 (64,2048,128)

    const size_t wxt_bytes = (size_t)GATES * IN_DIM * sizeof(f16);  // 128 KiB
    const size_t wht_bytes = (size_t)GATES * IN_DIM * sizeof(f16);  // 128 KiB
    const size_t xp_bytes  = (size_t)ROWS * GATES * sizeof(f16);    // 128 MiB
    if (ws_size >= wxt_bytes + wht_bytes + xp_bytes) {
        f16* WxT = (f16*)d_ws;
        f16* WhT = (f16*)((char*)d_ws + wxt_bytes);
        f16* xp  = (f16*)((char*)d_ws + wxt_bytes + wht_bytes);
        hipLaunchKernelGGL(wt_kernel, dim3(512), dim3(256), 0, stream, W, WxT, WhT);
        hipLaunchKernelGGL(xp_gemm, dim3(ROWS / 128), dim3(256), 0, stream,
                           data, WxT, bias, xp);
        hipLaunchKernelGGL(lstm_scan_mfma, dim3(4), dim3(512), 0, stream,
                           WhT, xp, out);
    } else {
        // Workspace too small: fused fallback (all weights register-resident).
        hipLaunchKernelGGL(lstm_scan_fused, dim3(BATCH), dim3(256), 0, stream,
                           W, bias, data, out);
    }
}

// Round 3
// 2202.573 us; speedup vs baseline: 1.0647x; 1.0647x over previous
//
#include <hip/hip_runtime.h>
#include <cstdint>

#define UNITS 128
#define GATES 512            // 4*UNITS
#define IN_DIM 128
#define BATCH 64
#define SEQ 2048
#define ROWS (BATCH * SEQ)   // 131072

typedef _Float16 f16;
typedef _Float16 f16x2 __attribute__((ext_vector_type(2)));
typedef _Float16 f16x8 __attribute__((ext_vector_type(8)));
typedef float    f32x4 __attribute__((ext_vector_type(4)));

static __device__ __forceinline__ float sigmoid_f(float x) {
    float e = __builtin_amdgcn_exp2f(-1.44269504f * x);
    return __builtin_amdgcn_rcpf(1.0f + e);
}
static __device__ __forceinline__ float tanh_f(float x) {
    float e = __builtin_amdgcn_exp2f(2.8853900817779268f * x);
    return 1.0f - 2.0f * __builtin_amdgcn_rcpf(1.0f + e);
}

// Workgroup barrier that orders LDS only: skips __syncthreads()'s
// s_waitcnt vmcnt(0), so xp prefetch and out[] stores stay in flight.
static __device__ __forceinline__ void lds_barrier() {
    __asm__ volatile("s_waitcnt lgkmcnt(0)\n\ts_barrier" ::: "memory");
}

// ---------------------------------------------------------------------------
// Kernel 1: WxT[n][k] = (f16)Wx[k][n]  — f32 coalesced read, f16 transpose out
// (round-0 verified version)
// ---------------------------------------------------------------------------
__global__ void wxt_kernel(const float* __restrict__ W,
                           f16* __restrict__ WxT) {
    int idx = blockIdx.x * 256 + threadIdx.x;     // 0 .. 65535 over Wx (128x512)
    int k = idx >> 9, n = idx & 511;              // coalesced read of W[idx]
    WxT[n * IN_DIM + k] = (f16)W[idx];
}

// ---------------------------------------------------------------------------
// Kernel 2: xp = data @ Wx + b, f16 out (ROWS x 512), LINEAR layout.
// (round-0 verified version, restored)
// ---------------------------------------------------------------------------
__global__ __launch_bounds__(256) void xp_gemm(
        const float* __restrict__ A,      // data f32, ROWS x 128
        const f16*  __restrict__ WxT,     // 512 x 128 f16
        const float* __restrict__ bias,   // 512 f32
        f16* __restrict__ xp) {
    const int wave = threadIdx.x >> 6;
    const int lane = threadIdx.x & 63;
    const int m16  = lane & 15;
    const int q    = lane >> 4;
    const int rowBase = blockIdx.x * 128 + wave * 32;

    f16x8 a[2][4];
    #pragma unroll
    for (int mc = 0; mc < 2; ++mc)
        #pragma unroll
        for (int ks = 0; ks < 4; ++ks) {
            const float* p = A + (size_t)(rowBase + mc * 16 + m16) * IN_DIM
                               + ks * 32 + q * 8;
            float4 lo = *(const float4*)p;
            float4 hi = *(const float4*)(p + 4);
            f16x8 v;
            v[0] = (f16)lo.x; v[1] = (f16)lo.y; v[2] = (f16)lo.z; v[3] = (f16)lo.w;
            v[4] = (f16)hi.x; v[5] = (f16)hi.y; v[6] = (f16)hi.z; v[7] = (f16)hi.w;
            a[mc][ks] = v;
        }

    for (int nt = 0; nt < 32; ++nt) {
        f16x8 bfr[4];
        #pragma unroll
        for (int ks = 0; ks < 4; ++ks)
            bfr[ks] = *(const f16x8*)(WxT + (nt * 16 + m16) * IN_DIM + ks * 32 + q * 8);
        f32x4 acc0 = {0.f, 0.f, 0.f, 0.f}, acc1 = {0.f, 0.f, 0.f, 0.f};
        #pragma unroll
        for (int ks = 0; ks < 4; ++ks) {
            acc0 = __builtin_amdgcn_mfma_f32_16x16x32_f16(a[0][ks], bfr[ks], acc0, 0, 0, 0);
            acc1 = __builtin_amdgcn_mfma_f32_16x16x32_f16(a[1][ks], bfr[ks], acc1, 0, 0, 0);
        }
        float bv = bias[nt * 16 + m16];
        #pragma unroll
        for (int r = 0; r < 4; ++r) {
            int row0 = rowBase + q * 4 + r;
            xp[(size_t)row0 * GATES + nt * 16 + m16]        = (f16)(acc0[r] + bv);
            xp[(size_t)(row0 + 16) * GATES + nt * 16 + m16] = (f16)(acc1[r] + bv);
        }
    }
}

// ---------------------------------------------------------------------------
// Kernel 3 (NEW): TWO-STREAM scan. 32 blocks x 2 samples, 4 waves (256 thr).
//
// Round-3 theory: per-sample-step ISSUE is ~450-550 cy/SIMD and invariant to
// wave count; round-0's 1400-cy ring was ~50% issue + ~50% serial-dependency
// stall (LDS h round-trip, exp/rcp chains, barrier). MFMA can't help (M<16
// padding keeps the matrix pipe at ~620 cy/SIMD; M=16 drowns the VALU on 4
// CUs — round 2). The untapped resource: interleave TWO independent samples
// in the same waves so stream B's issue fills stream A's stall gaps.
// Weights (128 VGPRs) shared; per-stream state: c, 4 xp prefetch regs,
// h double-buffer in LDS. One lds_barrier covers both streams.
//
// Per-lane layout (round-0 verified): half = lane>>5, cell = wave*32+(lane&31)
//   half==0 -> cols {cell (i), cell+128 (f)};  half==1 -> {+256 (o), +384 (g)}
// Gate exchange: two shfl_xor(.,32) per stream. Nonlinearity on z1 is
// branchless (per-lane m/A/B constants select sigmoid vs tanh).
// ---------------------------------------------------------------------------
__global__ __launch_bounds__(256, 1) void lstm_scan2(
        const float* __restrict__ W,      // 256 x 512 f32 (rows 128.. = Wh)
        const f16* __restrict__ xp,       // ROWS x 512 f16 (linear)
        float* __restrict__ out) {        // ROWS x 128 f32
    __shared__ __align__(16) f16 h_lds[2][2][UNITS];   // [stream][buf][cell]

    const int tid  = threadIdx.x;
    const int wave = tid >> 6;
    const int lane = tid & 63;
    const int half = lane >> 5;                 // 0: {i,f}  1: {o,g}
    const int cell = wave * 32 + (lane & 31);   // j in [0,128)
    const int c0   = cell + half * 256;         // i_j  or  o_j
    const int c1   = c0 + 128;                  // f_j  or  g_j
    const int bA   = blockIdx.x * 2;
    const int bB   = bA + 1;

    // Wh columns c0, c1 -> 128 VGPRs as f16 pairs, SHARED by both streams.
    f16x2 wh0[64], wh1[64];
    #pragma unroll
    for (int k = 0; k < 64; ++k) {
        wh0[k] = f16x2{(f16)W[(size_t)(IN_DIM + 2 * k) * GATES + c0],
                       (f16)W[(size_t)(IN_DIM + 2 * k + 1) * GATES + c0]};
        wh1[k] = f16x2{(f16)W[(size_t)(IN_DIM + 2 * k) * GATES + c1],
                       (f16)W[(size_t)(IN_DIM + 2 * k + 1) * GATES + c1]};
    }

    // branchless constants for the z1 nonlinearity (f: sigmoid, g: tanh)
    const float m1 = (half == 0) ? -1.44269504f : 2.8853900817779268f;
    const float A1 = (half == 0) ? 0.0f : 1.0f;
    const float B1 = (half == 0) ? 1.0f : -2.0f;

    float cAc = 1.0f, cBc = 1.0f;                  // reference: c0 = ones
    if (tid < UNITS) {
        h_lds[0][0][tid] = (f16)0.f;               // h0 = zeros, both streams
        h_lds[1][0][tid] = (f16)0.f;
    }

    const f16* xpA = xp + (size_t)bA * SEQ * GATES;
    const f16* xpB = xp + (size_t)bB * SEQ * GATES;
    // xp prefetch pipeline, distance 2, per stream
    f16 a0c0 = xpA[c0], a0c1 = xpA[c1];
    f16 a1c0 = xpA[GATES + c0], a1c1 = xpA[GATES + c1];
    f16 b0c0 = xpB[c0], b0c1 = xpB[c1];
    f16 b1c0 = xpB[GATES + c0], b1c1 = xpB[GATES + c1];
    __syncthreads();     // once, before the loop

    for (int t = 0; t < SEQ; ++t) {
        const int cur = t & 1, nxt = cur ^ 1;

        float xcA0 = (float)a0c0, xcA1 = (float)a0c1;
        float xcB0 = (float)b0c0, xcB1 = (float)b0c1;
        a0c0 = a1c0; a0c1 = a1c1;
        b0c0 = b1c0; b0c1 = b1c1;
        int t2 = (t + 2 < SEQ) ? (t + 2) : (SEQ - 1);   // clamped, no OOB
        a1c0 = xpA[(size_t)t2 * GATES + c0];
        a1c1 = xpA[(size_t)t2 * GATES + c1];
        b1c0 = xpB[(size_t)t2 * GATES + c0];
        b1c1 = xpB[(size_t)t2 * GATES + c1];

        // ---- issue both h broadcasts up front (latency overlaps A's dots)
        const uint4* hsA = (const uint4*)(&h_lds[0][cur][0]);
        const uint4* hsB = (const uint4*)(&h_lds[1][cur][0]);
        uint4 hbA[16], hbB[16];
        #pragma unroll
        for (int i = 0; i < 16; ++i) hbA[i] = hsA[i];
        #pragma unroll
        for (int i = 0; i < 16; ++i) hbB[i] = hsB[i];

        // ---- dots, stream A (4 independent chains)
        float zA00 = xcA0, zA01 = 0.f, zA10 = xcA1, zA11 = 0.f;
        #pragma unroll
        for (int i = 0; i < 16; ++i) {
            f16x2 p0 = __builtin_bit_cast(f16x2, hbA[i].x);
            f16x2 p1 = __builtin_bit_cast(f16x2, hbA[i].y);
            f16x2 p2 = __builtin_bit_cast(f16x2, hbA[i].z);
            f16x2 p3 = __builtin_bit_cast(f16x2, hbA[i].w);
            const int k = 4 * i;
            if (i < 8) {
                zA00 = __builtin_amdgcn_fdot2(p0, wh0[k],     zA00, false);
                zA10 = __builtin_amdgcn_fdot2(p0, wh1[k],     zA10, false);
                zA00 = __builtin_amdgcn_fdot2(p1, wh0[k + 1], zA00, false);
                zA10 = __builtin_amdgcn_fdot2(p1, wh1[k + 1], zA10, false);
                zA00 = __builtin_amdgcn_fdot2(p2, wh0[k + 2], zA00, false);
                zA10 = __builtin_amdgcn_fdot2(p2, wh1[k + 2], zA10, false);
                zA00 = __builtin_amdgcn_fdot2(p3, wh0[k + 3], zA00, false);
                zA10 = __builtin_amdgcn_fdot2(p3, wh1[k + 3], zA10, false);
            } else {
                zA01 = __builtin_amdgcn_fdot2(p0, wh0[k],     zA01, false);
                zA11 = __builtin_amdgcn_fdot2(p0, wh1[k],     zA11, false);
                zA01 = __builtin_amdgcn_fdot2(p1, wh0[k + 1], zA01, false);
                zA11 = __builtin_amdgcn_fdot2(p1, wh1[k + 1], zA11, false);
                zA01 = __builtin_amdgcn_fdot2(p2, wh0[k + 2], zA01, false);
                zA11 = __builtin_amdgcn_fdot2(p2, wh1[k + 2], zA11, false);
                zA01 = __builtin_amdgcn_fdot2(p3, wh0[k + 3], zA01, false);
                zA11 = __builtin_amdgcn_fdot2(p3, wh1[k + 3], zA11, false);
            }
        }

        // ---- dots, stream B
        float zB00 = xcB0, zB01 = 0.f, zB10 = xcB1, zB11 = 0.f;
        #pragma unroll
        for (int i = 0; i < 16; ++i) {
            f16x2 p0 = __builtin_bit_cast(f16x2, hbB[i].x);
            f16x2 p1 = __builtin_bit_cast(f16x2, hbB[i].y);
            f16x2 p2 = __builtin_bit_cast(f16x2, hbB[i].z);
            f16x2 p3 = __builtin_bit_cast(f16x2, hbB[i].w);
            const int k = 4 * i;
            if (i < 8) {
                zB00 = __builtin_amdgcn_fdot2(p0, wh0[k],     zB00, false);
                zB10 = __builtin_amdgcn_fdot2(p0, wh1[k],     zB10, false);
                zB00 = __builtin_amdgcn_fdot2(p1, wh0[k + 1], zB00, false);
                zB10 = __builtin_amdgcn_fdot2(p1, wh1[k + 1], zB10, false);
                zB00 = __builtin_amdgcn_fdot2(p2, wh0[k + 2], zB00, false);
                zB10 = __builtin_amdgcn_fdot2(p2, wh1[k + 2], zB10, false);
                zB00 = __builtin_amdgcn_fdot2(p3, wh0[k + 3], zB00, false);
                zB10 = __builtin_amdgcn_fdot2(p3, wh1[k + 3], zB10, false);
            } else {
                zB01 = __builtin_amdgcn_fdot2(p0, wh0[k],     zB01, false);
                zB11 = __builtin_amdgcn_fdot2(p0, wh1[k],     zB11, false);
                zB01 = __builtin_amdgcn_fdot2(p1, wh0[k + 1], zB01, false);
                zB11 = __builtin_amdgcn_fdot2(p1, wh1[k + 1], zB11, false);
                zB01 = __builtin_amdgcn_fdot2(p2, wh0[k + 2], zB01, false);
                zB11 = __builtin_amdgcn_fdot2(p2, wh1[k + 2], zB11, false);
                zB01 = __builtin_amdgcn_fdot2(p3, wh0[k + 3], zB01, false);
                zB11 = __builtin_amdgcn_fdot2(p3, wh1[k + 3], zB11, false);
            }
        }

        // ---- nonlinearities + exchange, interleaved so B's trans/shuffle
        //      issue fills A's chain latency (and vice versa)
        float zA0 = zA00 + zA01, zA1 = zA10 + zA11;
        float zB0 = zB00 + zB01, zB1 = zB10 + zB11;

        float sA0 = sigmoid_f(zA0);
        float sB0 = sigmoid_f(zB0);
        float eA1 = __builtin_amdgcn_exp2f(m1 * zA1);
        float eB1 = __builtin_amdgcn_exp2f(m1 * zB1);
        float sA1 = B1 * __builtin_amdgcn_rcpf(1.0f + eA1) + A1;
        float sB1 = B1 * __builtin_amdgcn_rcpf(1.0f + eB1) + A1;

        float pA0 = __shfl_xor(sA0, 32, 64);   // partner's first  (o or i)
        float pB0 = __shfl_xor(sB0, 32, 64);
        float pA1 = __shfl_xor(sA1, 32, 64);   // partner's second (g or f)
        float pB1 = __shfl_xor(sB1, 32, 64);

        if (half == 0) {
            // this lane: sX0=sig(i), sX1=sig(f); partner: pX0=sig(o), pX1=tanh(g)
            cAc = sA1 * cAc + sA0 * pA1;
            cBc = sB1 * cBc + sB0 * pB1;
            float hA = pA0 * tanh_f(cAc);
            float hB = pB0 * tanh_f(cBc);
            h_lds[0][nxt][cell] = (f16)hA;
            h_lds[1][nxt][cell] = (f16)hB;
            out[((size_t)bA * SEQ + t) * UNITS + cell] = hA;
            out[((size_t)bB * SEQ + t) * UNITS + cell] = hB;
        }
        lds_barrier();   // LDS-only ordering: xp prefetch + out stores in flight
    }
}

// ---------------------------------------------------------------------------
// Fallback (workspace too small): fused 4-wave scan, weights register-resident.
// ---------------------------------------------------------------------------
__global__ __launch_bounds__(256, 1) void lstm_scan_fused(
        const float* __restrict__ W,      // 256 x 512 f32
        const float* __restrict__ bias,   // 512 f32
        const float* __restrict__ data,   // ROWS x 128 f32
        float* __restrict__ out) {        // ROWS x 128 f32
    __shared__ __align__(16) f16 h_lds[2][UNITS];
    __shared__ __align__(16) f16 x_lds[2][UNITS];

    const int tid  = threadIdx.x;
    const int b    = blockIdx.x;
    const int wave = tid >> 6;
    const int lane = tid & 63;
    const int half = lane >> 5;
    const int cell = wave * 32 + (lane & 31);
    const int c0   = cell + half * 256;
    const int c1   = c0 + 128;

    f16x2 wh0[64], wh1[64];
    #pragma unroll
    for (int k = 0; k < 64; ++k) {
        wh0[k] = f16x2{(f16)W[(size_t)(IN_DIM + 2 * k) * GATES + c0],
                       (f16)W[(size_t)(IN_DIM + 2 * k + 1) * GATES + c0]};
        wh1[k] = f16x2{(f16)W[(size_t)(IN_DIM + 2 * k) * GATES + c1],
                       (f16)W[(size_t)(IN_DIM + 2 * k + 1) * GATES + c1]};
    }
    f16x2 wxa[64], wxb[64];
    #pragma unroll
    for (int k = 0; k < 64; ++k) {
        wxa[k] = f16x2{(f16)W[(size_t)(2 * k) * GATES + c0],
                       (f16)W[(size_t)(2 * k + 1) * GATES + c0]};
        wxb[k] = f16x2{(f16)W[(size_t)(2 * k) * GATES + c1],
                       (f16)W[(size_t)(2 * k + 1) * GATES + c1]};
    }
    float bb0 = bias[c0];
    float bb1 = bias[c1];

    float c = 1.0f;
    if (tid < UNITS) h_lds[0][tid] = (f16)0.f;
    if (tid < UNITS)
        x_lds[0][tid] = (f16)data[(size_t)b * SEQ * IN_DIM + tid];
    __syncthreads();

    for (int t = 0; t < SEQ; ++t) {
        const int cur = t & 1, nxt = cur ^ 1;
        float a00 = bb0, a01 = 0.f, a10 = bb1, a11 = 0.f;

        {
            const uint4* xsrc = (const uint4*)(&x_lds[cur][0]);
            uint4 xb[16];
            #pragma unroll
            for (int i = 0; i < 16; ++i) xb[i] = xsrc[i];
            #pragma unroll
            for (int i = 0; i < 16; ++i) {
                f16x2 p0 = __builtin_bit_cast(f16x2, xb[i].x);
                f16x2 p1 = __builtin_bit_cast(f16x2, xb[i].y);
                f16x2 p2 = __builtin_bit_cast(f16x2, xb[i].z);
                f16x2 p3 = __builtin_bit_cast(f16x2, xb[i].w);
                const int k = 4 * i;
                if (i < 8) {
                    a00 = __builtin_amdgcn_fdot2(p0, wxa[k],     a00, false);
                    a10 = __builtin_amdgcn_fdot2(p0, wxb[k],     a10, false);
                    a00 = __builtin_amdgcn_fdot2(p1, wxa[k + 1], a00, false);
                    a10 = __builtin_amdgcn_fdot2(p1, wxb[k + 1], a10, false);
                    a00 = __builtin_amdgcn_fdot2(p2, wxa[k + 2], a00, false);
                    a10 = __builtin_amdgcn_fdot2(p2, wxb[k + 2], a10, false);
                    a00 = __builtin_amdgcn_fdot2(p3, wxa[k + 3], a00, false);
                    a10 = __builtin_amdgcn_fdot2(p3, wxb[k + 3], a10, false);
                } else {
                    a01 = __builtin_amdgcn_fdot2(p0, wxa[k],     a01, false);
                    a11 = __builtin_amdgcn_fdot2(p0, wxb[k],     a11, false);
                    a01 = __builtin_amdgcn_fdot2(p1, wxa[k + 1], a01, false);
                    a11 = __builtin_amdgcn_fdot2(p1, wxb[k + 1], a11, false);
                    a01 = __builtin_amdgcn_fdot2(p2, wxa[k + 2], a01, false);
                    a11 = __builtin_amdgcn_fdot2(p2, wxb[k + 2], a11, false);
                    a01 = __builtin_amdgcn_fdot2(p3, wxa[k + 3], a01, false);
                    a11 = __builtin_amdgcn_fdot2(p3, wxb[k + 3], a11, false);
                }
            }
        }
        {
            const uint4* hsrc = (const uint4*)(&h_lds[cur][0]);
            uint4 hb[16];
            #pragma unroll
            for (int i = 0; i < 16; ++i) hb[i] = hsrc[i];
            #pragma unroll
            for (int i = 0; i < 16; ++i) {
                f16x2 p0 = __builtin_bit_cast(f16x2, hb[i].x);
                f16x2 p1 = __builtin_bit_cast(f16x2, hb[i].y);
                f16x2 p2 = __builtin_bit_cast(f16x2, hb[i].z);
                f16x2 p3 = __builtin_bit_cast(f16x2, hb[i].w);
                const int k = 4 * i;
                if (i < 8) {
                    a00 = __builtin_amdgcn_fdot2(p0, wh0[k],     a00, false);
                    a10 = __builtin_amdgcn_fdot2(p0, wh1[k],     a10, false);
                    a00 = __builtin_amdgcn_fdot2(p1, wh0[k + 1], a00, false);
                    a10 = __builtin_amdgcn_fdot2(p1, wh1[k + 1], a10, false);
                    a00 = __builtin_amdgcn_fdot2(p2, wh0[k + 2], a00, false);
                    a10 = __builtin_amdgcn_fdot2(p2, wh1[k + 2], a10, false);
                    a00 = __builtin_amdgcn_fdot2(p3, wh0[k + 3], a00, false);
                    a10 = __builtin_amdgcn_fdot2(p3, wh1[k + 3], a10, false);
                } else {
                    a01 = __builtin_amdgcn_fdot2(p0, wh0[k],     a01, false);
                    a11 = __builtin_amdgcn_fdot2(p0, wh1[k],     a11, false);
                    a01 = __builtin_amdgcn_fdot2(p1, wh0[k + 1], a01, false);
                    a11 = __builtin_amdgcn_fdot2(p1, wh1[k + 1], a11, false);
                    a01 = __builtin_amdgcn_fdot2(p2, wh0[k + 2], a01, false);
                    a11 = __builtin_amdgcn_fdot2(p2, wh1[k + 2], a11, false);
                    a01 = __builtin_amdgcn_fdot2(p3, wh0[k + 3], a01, false);
                    a11 = __builtin_amdgcn_fdot2(p3, wh1[k + 3], a11, false);
                }
            }
        }
        float z0 = a00 + a01, z1 = a10 + a11;

        float s0 = sigmoid_f(z0);
        float s1 = (half == 0) ? sigmoid_f(z1) : tanh_f(z1);
        float p0 = __shfl_xor(s0, 32, 64);
        float p1 = __shfl_xor(s1, 32, 64);

        if (half == 0) {
            c = s1 * c + s0 * p1;
            float h = p0 * tanh_f(c);
            h_lds[nxt][cell] = (f16)h;
            out[((size_t)b * SEQ + t) * UNITS + cell] = h;
        }
        if (tid < UNITS) {
            int t1 = (t + 1 < SEQ) ? (t + 1) : t;
            x_lds[nxt][tid] = (f16)data[(size_t)b * SEQ * IN_DIM
                                        + (size_t)t1 * IN_DIM + tid];
        }
        lds_barrier();
    }
}

// ---------------------------------------------------------------------------
extern "C" void kernel_launch(void* const* d_in, const int* in_sizes, int n_in,
                              void* d_out, int out_size, void* d_ws, size_t ws_size,
                              hipStream_t stream) {
    const float* data = (const float*)d_in[0];   // f32 (64,2048,128)
    const float* W    = (const float*)d_in[1];   // f32 (256,512)
    const float* bias = (const float*)d_in[2];   // f32 (512,)
    float* out = (float*)d_out;                  // f32 (64,2048,128)

    const size_t wxt_bytes = (size_t)GATES * IN_DIM * sizeof(f16);  // 128 KiB
    const size_t xp_bytes  = (size_t)ROWS * GATES * sizeof(f16);    // 128 MiB
    if (ws_size >= wxt_bytes + xp_bytes) {
        f16* WxT = (f16*)d_ws;
        f16* xp  = (f16*)((char*)d_ws + wxt_bytes);
        hipLaunchKernelGGL(wxt_kernel, dim3(256), dim3(256), 0, stream, W, WxT);
        hipLaunchKernelGGL(xp_gemm, dim3(ROWS / 128), dim3(256), 0, stream,
                           data, WxT, bias, xp);
        hipLaunchKernelGGL(lstm_scan2, dim3(BATCH / 2), dim3(256), 0, stream,
                           W, xp, out);
    } else {
        // Workspace too small: fused fallback (all weights register-resident).
        hipLaunchKernelGGL(lstm_scan_fused, dim3(BATCH), dim3(256), 0, stream,
                           W, bias, data, out);
    }
}

// Round 4
// 1294.720 us; speedup vs baseline: 1.8112x; 1.7012x over previous
//
#include <hip/hip_runtime.h>
#include <cstdint>

#define UNITS 128
#define GATES 512            // 4*UNITS
#define IN_DIM 128
#define BATCH 64
#define SEQ 2048
#define ROWS (BATCH * SEQ)   // 131072

typedef _Float16 f16;
typedef _Float16 f16x2 __attribute__((ext_vector_type(2)));
typedef _Float16 f16x4 __attribute__((ext_vector_type(4)));
typedef _Float16 f16x8 __attribute__((ext_vector_type(8)));
typedef float    f32x4 __attribute__((ext_vector_type(4)));

static __device__ __forceinline__ float sigmoid_f(float x) {
    float e = __builtin_amdgcn_exp2f(-1.44269504f * x);
    return __builtin_amdgcn_rcpf(1.0f + e);
}
static __device__ __forceinline__ float tanh_f(float x) {
    float e = __builtin_amdgcn_exp2f(2.8853900817779268f * x);
    return 1.0f - 2.0f * __builtin_amdgcn_rcpf(1.0f + e);
}

// Workgroup barrier that orders LDS only: skips __syncthreads()'s
// s_waitcnt vmcnt(0), so xp prefetch and out[] stores stay in flight.
static __device__ __forceinline__ void lds_barrier() {
    __asm__ volatile("s_waitcnt lgkmcnt(0)\n\ts_barrier" ::: "memory");
}

// ---------------------------------------------------------------------------
// Kernel 1: WxT[n][k] = (f16)Wx[k][n]  — f32 coalesced read, f16 transpose out
// (round-0 verified version)
// ---------------------------------------------------------------------------
__global__ void wxt_kernel(const float* __restrict__ W,
                           f16* __restrict__ WxT) {
    int idx = blockIdx.x * 256 + threadIdx.x;     // 0 .. 65535 over Wx (128x512)
    int k = idx >> 9, n = idx & 511;              // coalesced read of W[idx]
    WxT[n * IN_DIM + k] = (f16)W[idx];
}

// ---------------------------------------------------------------------------
// Kernel 2: xp = data @ Wx + b, f16, TRANSPOSED layout xp[b][col][t]
// (round-0 verified compute; store addressing changed to [b][col][t] which
// turns 8 scattered 2B stores into 2 × 8B vector stores — 4 consecutive t,
// same col, 8B-aligned since t0 % 4 == 0.)
// ---------------------------------------------------------------------------
__global__ __launch_bounds__(256) void xp_gemm(
        const float* __restrict__ A,      // data f32, ROWS x 128
        const f16*  __restrict__ WxT,     // 512 x 128 f16
        const float* __restrict__ bias,   // 512 f32
        f16* __restrict__ xp) {           // [64][512][2048] f16
    const int wave = threadIdx.x >> 6;
    const int lane = threadIdx.x & 63;
    const int m16  = lane & 15;
    const int q    = lane >> 4;
    const int rowBase = blockIdx.x * 128 + wave * 32;   // 128 | 2048: one sample
    const int bidx = rowBase >> 11;                     // sample index
    const int tBase = (rowBase & 2047) + q * 4;

    f16x8 a[2][4];
    #pragma unroll
    for (int mc = 0; mc < 2; ++mc)
        #pragma unroll
        for (int ks = 0; ks < 4; ++ks) {
            const float* p = A + (size_t)(rowBase + mc * 16 + m16) * IN_DIM
                               + ks * 32 + q * 8;
            float4 lo = *(const float4*)p;
            float4 hi = *(const float4*)(p + 4);
            f16x8 v;
            v[0] = (f16)lo.x; v[1] = (f16)lo.y; v[2] = (f16)lo.z; v[3] = (f16)lo.w;
            v[4] = (f16)hi.x; v[5] = (f16)hi.y; v[6] = (f16)hi.z; v[7] = (f16)hi.w;
            a[mc][ks] = v;
        }

    for (int nt = 0; nt < 32; ++nt) {
        f16x8 bfr[4];
        #pragma unroll
        for (int ks = 0; ks < 4; ++ks)
            bfr[ks] = *(const f16x8*)(WxT + (nt * 16 + m16) * IN_DIM + ks * 32 + q * 8);
        f32x4 acc0 = {0.f, 0.f, 0.f, 0.f}, acc1 = {0.f, 0.f, 0.f, 0.f};
        #pragma unroll
        for (int ks = 0; ks < 4; ++ks) {
            acc0 = __builtin_amdgcn_mfma_f32_16x16x32_f16(a[0][ks], bfr[ks], acc0, 0, 0, 0);
            acc1 = __builtin_amdgcn_mfma_f32_16x16x32_f16(a[1][ks], bfr[ks], acc1, 0, 0, 0);
        }
        const int col = nt * 16 + m16;
        float bv = bias[col];
        f16x4 v0, v1;
        #pragma unroll
        for (int r = 0; r < 4; ++r) {
            v0[r] = (f16)(acc0[r] + bv);
            v1[r] = (f16)(acc1[r] + bv);
        }
        f16* dst = xp + ((size_t)bidx * GATES + col) * SEQ + tBase;
        *(f16x4*)(dst)      = v0;        // rows rowBase+q*4+r      -> t, t+1..t+3
        *(f16x4*)(dst + 16) = v1;        // rows rowBase+16+q*4+r   -> t+16..
    }
}

// ---------------------------------------------------------------------------
// Kernel 3: scan, round-0 champion structure (64 blocks x 1 sample, 4 waves)
// with tail polish. Model (fits R0-R3 measurements): v_dot2_f32_f16 is
// half-rate (~4cy/wave-instr) -> dots are a fixed 512 cy/SIMD/step; per-CU
// issue is the wall, so 64 blocks (max CUs) is optimal and the only headroom
// is the ~450-500 cy of exposed tail latency + removable issue:
//   * branchless z1 nonlinearity (no divergent dual-path trans)  [R3-verified]
//   * both halves redundantly compute c,h (bitwise-identical op sequence):
//     half0 does only the critical ds_write(h); half1 does the out[] store,
//     taking out-addressing off the h->barrier critical path
//   * xp transposed [b][col][t]: 2 x dwordx4 loads per 8 steps replace 16
//     scalar loads + addressing; t-loop unrolled 8x so extracts are static
// ---------------------------------------------------------------------------
__global__ __launch_bounds__(256, 1) void lstm_scan_v5(
        const float* __restrict__ W,      // 256 x 512 f32 (rows 128.. = Wh)
        const f16* __restrict__ xpt,      // [64][512][2048] f16
        float* __restrict__ out) {        // ROWS x 128 f32
    __shared__ __align__(16) f16 h_lds[2][UNITS];

    const int tid  = threadIdx.x;
    const int b    = blockIdx.x;
    const int wave = tid >> 6;
    const int lane = tid & 63;
    const int half = lane >> 5;                 // 0: {i,f}  1: {o,g}
    const int cell = wave * 32 + (lane & 31);   // j in [0,128)
    const int c0   = cell + half * 256;         // i_j  or  o_j
    const int c1   = c0 + 128;                  // f_j  or  g_j

    // Wh columns c0, c1 -> 128 VGPRs as f16 pairs. FULLY unrolled.
    f16x2 wh0[64], wh1[64];
    #pragma unroll
    for (int k = 0; k < 64; ++k) {
        wh0[k] = f16x2{(f16)W[(size_t)(IN_DIM + 2 * k) * GATES + c0],
                       (f16)W[(size_t)(IN_DIM + 2 * k + 1) * GATES + c0]};
        wh1[k] = f16x2{(f16)W[(size_t)(IN_DIM + 2 * k) * GATES + c1],
                       (f16)W[(size_t)(IN_DIM + 2 * k + 1) * GATES + c1]};
    }

    // branchless constants for the z1 nonlinearity (f: sigmoid, g: tanh)
    const float m1 = (half == 0) ? -1.44269504f : 2.8853900817779268f;
    const float A1 = (half == 0) ? 0.0f : 1.0f;
    const float B1 = (half == 0) ? 1.0f : -2.0f;

    float c = 1.0f;                                // reference: c0 = ones
    if (tid < UNITS) h_lds[0][tid] = (f16)0.f;     // h0 = zeros

    // xp: per-lane column streams, 8 timesteps per 16B load
    const f16* xa = xpt + ((size_t)b * GATES + c0) * SEQ;
    const f16* xb = xpt + ((size_t)b * GATES + c1) * SEQ;
    f16x8 x0cur = *(const f16x8*)(xa);
    f16x8 x1cur = *(const f16x8*)(xb);
    f16x8 x0nxt = *(const f16x8*)(xa + 8);
    f16x8 x1nxt = *(const f16x8*)(xb + 8);
    __syncthreads();     // once, before the loop

    for (int w = 0; w < SEQ / 8; ++w) {
        // prefetch window w+2 (clamped; ~2 windows ≈ 19k cy of cover)
        const int wn = (w + 2 < SEQ / 8) ? (w + 2) : (SEQ / 8 - 1);
        f16x8 x0pf = *(const f16x8*)(xa + (size_t)wn * 8);
        f16x8 x1pf = *(const f16x8*)(xb + (size_t)wn * 8);

        #pragma unroll
        for (int u = 0; u < 8; ++u) {
            const int cur = u & 1, nxt = cur ^ 1;   // w*8 even -> t&1 == u&1
            const float xc0 = (float)x0cur[u];      // static extract (no scratch)
            const float xc1 = (float)x1cur[u];

            // h broadcast: 16 x 16B LDS reads, same address across all lanes.
            const uint4* hsrc = (const uint4*)(&h_lds[cur][0]);
            uint4 hb[16];
            #pragma unroll
            for (int i = 0; i < 16; ++i) hb[i] = hsrc[i];

            float a00 = xc0, a01 = 0.f, a10 = xc1, a11 = 0.f;
            #pragma unroll
            for (int i = 0; i < 16; ++i) {
                f16x2 p0 = __builtin_bit_cast(f16x2, hb[i].x);
                f16x2 p1 = __builtin_bit_cast(f16x2, hb[i].y);
                f16x2 p2 = __builtin_bit_cast(f16x2, hb[i].z);
                f16x2 p3 = __builtin_bit_cast(f16x2, hb[i].w);
                const int k = 4 * i;
                if (i < 8) {                     // 4 independent chains
                    a00 = __builtin_amdgcn_fdot2(p0, wh0[k],     a00, false);
                    a10 = __builtin_amdgcn_fdot2(p0, wh1[k],     a10, false);
                    a00 = __builtin_amdgcn_fdot2(p1, wh0[k + 1], a00, false);
                    a10 = __builtin_amdgcn_fdot2(p1, wh1[k + 1], a10, false);
                    a00 = __builtin_amdgcn_fdot2(p2, wh0[k + 2], a00, false);
                    a10 = __builtin_amdgcn_fdot2(p2, wh1[k + 2], a10, false);
                    a00 = __builtin_amdgcn_fdot2(p3, wh0[k + 3], a00, false);
                    a10 = __builtin_amdgcn_fdot2(p3, wh1[k + 3], a10, false);
                } else {
                    a01 = __builtin_amdgcn_fdot2(p0, wh0[k],     a01, false);
                    a11 = __builtin_amdgcn_fdot2(p0, wh1[k],     a11, false);
                    a01 = __builtin_amdgcn_fdot2(p1, wh0[k + 1], a01, false);
                    a11 = __builtin_amdgcn_fdot2(p1, wh1[k + 1], a11, false);
                    a01 = __builtin_amdgcn_fdot2(p2, wh0[k + 2], a01, false);
                    a11 = __builtin_amdgcn_fdot2(p2, wh1[k + 2], a11, false);
                    a01 = __builtin_amdgcn_fdot2(p3, wh0[k + 3], a01, false);
                    a11 = __builtin_amdgcn_fdot2(p3, wh1[k + 3], a11, false);
                }
            }
            float z0 = a00 + a01, z1 = a10 + a11;

            // nonlinearities (branchless z1) + exchange
            float s0 = sigmoid_f(z0);
            float e1 = __builtin_amdgcn_exp2f(m1 * z1);
            float s1 = B1 * __builtin_amdgcn_rcpf(1.0f + e1) + A1;
            float p0 = __shfl_xor(s0, 32, 64);   // partner's first  (o or i)
            float p1 = __shfl_xor(s1, 32, 64);   // partner's second (g or f)

            // both halves compute c,h via the SAME f32 op sequence
            // (bitwise identical), so either half's h is valid:
            //   half0: s0=sig(i) s1=sig(f) p0=sig(o) p1=tanh(g)
            //   half1: s0=sig(o) s1=tanh(g) p0=sig(i) p1=sig(f)
            float fi = (half == 0) ? s1 : p1;    // sig(f)
            float ii = (half == 0) ? s0 : p0;    // sig(i)
            float gg = (half == 0) ? p1 : s1;    // tanh(g)
            float oo = (half == 0) ? p0 : s0;    // sig(o)
            c = fi * c + ii * gg;
            float h = oo * tanh_f(c);

            if (half == 0) {
                h_lds[nxt][cell] = (f16)h;       // critical path: h -> barrier
            } else {
                out[((size_t)b * SEQ + w * 8 + u) * UNITS + cell] = h;
            }
            lds_barrier();   // LDS-only ordering: loads/stores stay in flight
        }
        x0cur = x0nxt; x1cur = x1nxt;
        x0nxt = x0pf;  x1nxt = x1pf;
    }
}

// ---------------------------------------------------------------------------
// Fallback (workspace too small): fused 4-wave scan, weights register-resident.
// ---------------------------------------------------------------------------
__global__ __launch_bounds__(256, 1) void lstm_scan_fused(
        const float* __restrict__ W,      // 256 x 512 f32
        const float* __restrict__ bias,   // 512 f32
        const float* __restrict__ data,   // ROWS x 128 f32
        float* __restrict__ out) {        // ROWS x 128 f32
    __shared__ __align__(16) f16 h_lds[2][UNITS];
    __shared__ __align__(16) f16 x_lds[2][UNITS];

    const int tid  = threadIdx.x;
    const int b    = blockIdx.x;
    const int wave = tid >> 6;
    const int lane = tid & 63;
    const int half = lane >> 5;
    const int cell = wave * 32 + (lane & 31);
    const int c0   = cell + half * 256;
    const int c1   = c0 + 128;

    f16x2 wh0[64], wh1[64];
    #pragma unroll
    for (int k = 0; k < 64; ++k) {
        wh0[k] = f16x2{(f16)W[(size_t)(IN_DIM + 2 * k) * GATES + c0],
                       (f16)W[(size_t)(IN_DIM + 2 * k + 1) * GATES + c0]};
        wh1[k] = f16x2{(f16)W[(size_t)(IN_DIM + 2 * k) * GATES + c1],
                       (f16)W[(size_t)(IN_DIM + 2 * k + 1) * GATES + c1]};
    }
    f16x2 wxa[64], wxb[64];
    #pragma unroll
    for (int k = 0; k < 64; ++k) {
        wxa[k] = f16x2{(f16)W[(size_t)(2 * k) * GATES + c0],
                       (f16)W[(size_t)(2 * k + 1) * GATES + c0]};
        wxb[k] = f16x2{(f16)W[(size_t)(2 * k) * GATES + c1],
                       (f16)W[(size_t)(2 * k + 1) * GATES + c1]};
    }
    float bb0 = bias[c0];
    float bb1 = bias[c1];

    float c = 1.0f;
    if (tid < UNITS) h_lds[0][tid] = (f16)0.f;
    if (tid < UNITS)
        x_lds[0][tid] = (f16)data[(size_t)b * SEQ * IN_DIM + tid];
    __syncthreads();

    for (int t = 0; t < SEQ; ++t) {
        const int cur = t & 1, nxt = cur ^ 1;
        float a00 = bb0, a01 = 0.f, a10 = bb1, a11 = 0.f;

        {
            const uint4* xsrc = (const uint4*)(&x_lds[cur][0]);
            uint4 xb[16];
            #pragma unroll
            for (int i = 0; i < 16; ++i) xb[i] = xsrc[i];
            #pragma unroll
            for (int i = 0; i < 16; ++i) {
                f16x2 p0 = __builtin_bit_cast(f16x2, xb[i].x);
                f16x2 p1 = __builtin_bit_cast(f16x2, xb[i].y);
                f16x2 p2 = __builtin_bit_cast(f16x2, xb[i].z);
                f16x2 p3 = __builtin_bit_cast(f16x2, xb[i].w);
                const int k = 4 * i;
                if (i < 8) {
                    a00 = __builtin_amdgcn_fdot2(p0, wxa[k],     a00, false);
                    a10 = __builtin_amdgcn_fdot2(p0, wxb[k],     a10, false);
                    a00 = __builtin_amdgcn_fdot2(p1, wxa[k + 1], a00, false);
                    a10 = __builtin_amdgcn_fdot2(p1, wxb[k + 1], a10, false);
                    a00 = __builtin_amdgcn_fdot2(p2, wxa[k + 2], a00, false);
                    a10 = __builtin_amdgcn_fdot2(p2, wxb[k + 2], a10, false);
                    a00 = __builtin_amdgcn_fdot2(p3, wxa[k + 3], a00, false);
                    a10 = __builtin_amdgcn_fdot2(p3, wxb[k + 3], a10, false);
                } else {
                    a01 = __builtin_amdgcn_fdot2(p0, wxa[k],     a01, false);
                    a11 = __builtin_amdgcn_fdot2(p0, wxb[k],     a11, false);
                    a01 = __builtin_amdgcn_fdot2(p1, wxa[k + 1], a01, false);
                    a11 = __builtin_amdgcn_fdot2(p1, wxb[k + 1], a11, false);
                    a01 = __builtin_amdgcn_fdot2(p2, wxa[k + 2], a01, false);
                    a11 = __builtin_amdgcn_fdot2(p2, wxb[k + 2], a11, false);
                    a01 = __builtin_amdgcn_fdot2(p3, wxa[k + 3], a01, false);
                    a11 = __builtin_amdgcn_fdot2(p3, wxb[k + 3], a11, false);
                }
            }
        }
        {
            const uint4* hsrc = (const uint4*)(&h_lds[cur][0]);
            uint4 hb[16];
            #pragma unroll
            for (int i = 0; i < 16; ++i) hb[i] = hsrc[i];
            #pragma unroll
            for (int i = 0; i < 16; ++i) {
                f16x2 p0 = __builtin_bit_cast(f16x2, hb[i].x);
                f16x2 p1 = __builtin_bit_cast(f16x2, hb[i].y);
                f16x2 p2 = __builtin_bit_cast(f16x2, hb[i].z);
                f16x2 p3 = __builtin_bit_cast(f16x2, hb[i].w);
                const int k = 4 * i;
                if (i < 8) {
                    a00 = __builtin_amdgcn_fdot2(p0, wh0[k],     a00, false);
                    a10 = __builtin_amdgcn_fdot2(p0, wh1[k],     a10, false);
                    a00 = __builtin_amdgcn_fdot2(p1, wh0[k + 1], a00, false);
                    a10 = __builtin_amdgcn_fdot2(p1, wh1[k + 1], a10, false);
                    a00 = __builtin_amdgcn_fdot2(p2, wh0[k + 2], a00, false);
                    a10 = __builtin_amdgcn_fdot2(p2, wh1[k + 2], a10, false);
                    a00 = __builtin_amdgcn_fdot2(p3, wh0[k + 3], a00, false);
                    a10 = __builtin_amdgcn_fdot2(p3, wh1[k + 3], a10, false);
                } else {
                    a01 = __builtin_amdgcn_fdot2(p0, wh0[k],     a01, false);
                    a11 = __builtin_amdgcn_fdot2(p0, wh1[k],     a11, false);
                    a01 = __builtin_amdgcn_fdot2(p1, wh0[k + 1], a01, false);
                    a11 = __builtin_amdgcn_fdot2(p1, wh1[k + 1], a11, false);
                    a01 = __builtin_amdgcn_fdot2(p2, wh0[k + 2], a01, false);
                    a11 = __builtin_amdgcn_fdot2(p2, wh1[k + 2], a11, false);
                    a01 = __builtin_amdgcn_fdot2(p3, wh0[k + 3], a01, false);
                    a11 = __builtin_amdgcn_fdot2(p3, wh1[k + 3], a11, false);
                }
            }
        }
        float z0 = a00 + a01, z1 = a10 + a11;

        float s0 = sigmoid_f(z0);
        float s1 = (half == 0) ? sigmoid_f(z1) : tanh_f(z1);
        float p0 = __shfl_xor(s0, 32, 64);
        float p1 = __shfl_xor(s1, 32, 64);

        if (half == 0) {
            c = s1 * c + s0 * p1;
            float h = p0 * tanh_f(c);
            h_lds[nxt][cell] = (f16)h;
            out[((size_t)b * SEQ + t) * UNITS + cell] = h;
        }
        if (tid < UNITS) {
            int t1 = (t + 1 < SEQ) ? (t + 1) : t;
            x_lds[nxt][tid] = (f16)data[(size_t)b * SEQ * IN_DIM
                                        + (size_t)t1 * IN_DIM + tid];
        }
        lds_barrier();
    }
}

// ---------------------------------------------------------------------------
extern "C" void kernel_launch(void* const* d_in, const int* in_sizes, int n_in,
                              void* d_out, int out_size, void* d_ws, size_t ws_size,
                              hipStream_t stream) {
    const float* data = (const float*)d_in[0];   // f32 (64,2048,128)
    const float* W    = (const float*)d_in[1];   // f32 (256,512)
    const float* bias = (const float*)d_in[2];   // f32 (512,)
    float* out = (float*)d_out;                  // f32 (64,2048,128)

    const size_t wxt_bytes = (size_t)GATES * IN_DIM * sizeof(f16);  // 128 KiB
    const size_t xp_bytes  = (size_t)ROWS * GATES * sizeof(f16);    // 128 MiB
    if (ws_size >= wxt_bytes + xp_bytes) {
        f16* WxT = (f16*)d_ws;
        f16* xp  = (f16*)((char*)d_ws + wxt_bytes);
        hipLaunchKernelGGL(wxt_kernel, dim3(256), dim3(256), 0, stream, W, WxT);
        hipLaunchKernelGGL(xp_gemm, dim3(ROWS / 128), dim3(256), 0, stream,
                           data, WxT, bias, xp);
        hipLaunchKernelGGL(lstm_scan_v5, dim3(BATCH), dim3(256), 0, stream,
                           W, xp, out);
    } else {
        // Workspace too small: fused fallback (all weights register-resident).
        hipLaunchKernelGGL(lstm_scan_fused, dim3(BATCH), dim3(256), 0, stream,
                           W, bias, data, out);
    }
}